// Round 16
// baseline (2285.452 us; speedup 1.0000x reference)
//
#include <hip/hip_runtime.h>

#define TT 2048
#define HH 64
#define II 6
#define OO 6
#define NTHR 320   // 5 waves: XA(0) W0(1) WX(2) W1(3) WF(4); XA+WF share SIMD0

typedef float    f32x4 __attribute__((ext_vector_type(4)));
typedef float    f32x2 __attribute__((ext_vector_type(2)));
typedef _Float16 f16x8 __attribute__((ext_vector_type(8)));

__device__ __forceinline__ float fast_sig(float v) {
    return __builtin_amdgcn_rcpf(1.0f + __expf(-v));
}
__device__ __forceinline__ float fast_tanh(float v) {
    return 1.0f - 2.0f * __builtin_amdgcn_rcpf(__expf(2.0f * v) + 1.0f);
}

#define MFMA(a, b, c) __builtin_amdgcn_mfma_f32_16x16x32_f16((a), (b), (c), 0, 0, 0)

// LDS-only barrier: global loads/stores stay in flight across it.
#define LGKM_BARRIER() asm volatile("s_waitcnt lgkmcnt(0)\ns_barrier" ::: "memory")

__global__
__attribute__((amdgpu_flat_work_group_size(NTHR, NTHR)))
__attribute__((amdgpu_waves_per_eu(2)))   // cap VGPR at 256: no spill, 2-wave SIMD0 fits
void lstm_mfma_kernel(const float* __restrict__ x,
                      const float* __restrict__ Wih0, const float* __restrict__ Whh0,
                      const float* __restrict__ b0,
                      const float* __restrict__ Wih1, const float* __restrict__ Whh1,
                      const float* __restrict__ b1,
                      const float* __restrict__ W1, const float* __restrict__ bf1,
                      const float* __restrict__ W2, const float* __restrict__ bf2,
                      float* __restrict__ out)
{
    const int row  = blockIdx.x;      // one batch row per block
    const int tid  = threadIdx.x;
    const int wid  = tid >> 6;        // 0=XA 1=W0 2=WX 3=W1 4=WF
    const int lane = tid & 63;
    const int n    = lane & 15;       // MFMA col-lane (B-col / D-col)
    const int q    = lane >> 4;       // k-group: elems k = 8q..8q+7 (+32 for hi chunk)

    __shared__ __attribute__((aligned(16))) _Float16 H0[2][HH];
    __shared__ __attribute__((aligned(16))) _Float16 H1[2][HH];
    __shared__ __attribute__((aligned(16))) _Float16 Rb[HH];
    __shared__ __attribute__((aligned(16))) float    XG0[2][4 * HH];  // xg0 strip f32
    __shared__ __attribute__((aligned(16))) float    XG1[2][4 * HH];  // xg1 strip f32

    // all init + prologue done by wave 0, published by the single __syncthreads
    if (tid < HH) {
        H0[0][tid] = (_Float16)0.f; H0[1][tid] = (_Float16)0.f;
        H1[0][tid] = (_Float16)0.f; H1[1][tid] = (_Float16)0.f;
        Rb[tid]    = (_Float16)0.f;
    }

    // elem i <-> k = kbase + 8q + i (same map as A-frag reads, so it cancels)
    auto mk = [&](const float* W, int r, int ld, int kbase, int kmax, bool rok) {
        f16x8 f;
        #pragma unroll
        for (int i = 0; i < 8; ++i) {
            int kk = kbase + 8 * q + i;
            f[i] = (rok && kk < kmax) ? (_Float16)W[r * ld + kk] : (_Float16)0.f;
        }
        return f;
    };
    const f32x4 zero4 = {0.f, 0.f, 0.f, 0.f};

    f16x8 fragG[32], fragY[2];
    float bv[16];
    float bf2v = 0.f;
    #pragma unroll
    for (int m = 0; m < 16; ++m) bv[m] = 0.f;
    fragY[0] = mk(W1, 0, HH, 0, HH, false);   // zero
    fragY[1] = fragY[0];
    #pragma unroll
    for (int m = 0; m < 32; ++m) fragG[m] = fragY[0];

    if (wid == 0) {            // XA: Wih0 (k<6 only, 1 chunk) rows 16m+n
        #pragma unroll
        for (int m = 0; m < 16; ++m) {
            fragG[m] = mk(Wih0, 16 * m + n, II, 0, II, true);
            bv[m] = b0[16 * m + n];
        }
    } else if (wid == 1) {     // W0: Whh0 rows 16m+n, 2 k-chunks
        #pragma unroll
        for (int m = 0; m < 16; ++m) {
            fragG[2 * m + 0] = mk(Whh0, 16 * m + n, HH, 0,  HH, true);
            fragG[2 * m + 1] = mk(Whh0, 16 * m + n, HH, 32, HH, true);
        }
    } else if (wid == 2) {     // WX: Wih1 rows
        #pragma unroll
        for (int m = 0; m < 16; ++m) {
            fragG[2 * m + 0] = mk(Wih1, 16 * m + n, HH, 0,  HH, true);
            fragG[2 * m + 1] = mk(Wih1, 16 * m + n, HH, 32, HH, true);
            bv[m] = b1[16 * m + n];
        }
    } else if (wid == 3) {     // W1: Whh1 rows
        #pragma unroll
        for (int m = 0; m < 16; ++m) {
            fragG[2 * m + 0] = mk(Whh1, 16 * m + n, HH, 0,  HH, true);
            fragG[2 * m + 1] = mk(Whh1, 16 * m + n, HH, 32, HH, true);
        }
    } else {                   // WF: FC1 rows 16m+n (m<4) + FC2 row n
        #pragma unroll
        for (int m = 0; m < 4; ++m) {
            fragG[2 * m + 0] = mk(W1, 16 * m + n, HH, 0,  HH, true);
            fragG[2 * m + 1] = mk(W1, 16 * m + n, HH, 32, HH, true);
            bv[m] = bf1[16 * m + n];
        }
        fragY[0] = mk(W2, n, HH, 0,  HH, n < OO);
        fragY[1] = mk(W2, n, HH, 32, HH, n < OO);
        bf2v = (n < OO) ? bf2[n] : 0.f;
    }

    // x register pipeline (XA only); opaque VGPR ptr -> lazy vector loads
    const float* xrow = x + (size_t)row * TT * II;
    {
        unsigned long long p = (unsigned long long)xrow;
        asm volatile("" : "+v"(p));
        xrow = (const float*)p;
    }
    float xc[6] = {0.f, 0.f, 0.f, 0.f, 0.f, 0.f};

    if (wid == 0) {            // prologue: xg0[0] -> XG0 slot 0; xc = x[1]
        float x0[6];
        #pragma unroll
        for (int k2 = 0; k2 < 6; ++k2) x0[k2] = xrow[k2];
        f16x8 a2;
        #pragma unroll
        for (int i = 0; i < 6; ++i) a2[i] = (_Float16)x0[i];
        a2[6] = (_Float16)0.f; a2[7] = (_Float16)0.f;
        #pragma unroll
        for (int m = 0; m < 16; ++m) {
            f32x4 acc = MFMA(a2, fragG[m], zero4);
            if (lane < 16) XG0[0][16 * m + n] = acc[0] + bv[m];
        }
        #pragma unroll
        for (int k2 = 0; k2 < 6; ++k2) xc[k2] = xrow[II + k2];
    }

    float* outrow = out + (size_t)row * TT * OO;
    float cst[4] = {0.f, 0.f, 0.f, 0.f};   // W0/W1: cell state, 4 units/lane
    f16x8 rf0 = fragY[0], rf1 = fragY[0];  // WF: reg-carried r-frags (start zero-ish)
    if (wid == 4) { rf0 = mk(W1, 0, HH, 0, HH, false); rf1 = rf0; }

    __syncthreads();   // publish init + prologue

    // Slot algebra (all cross-wave handoffs are 1 epoch apart):
    //  XG0: XA@t writes xg0[t+1] -> slot (t+1)&1 ; W0@t reads xg0[t] -> slot t&1
    //  H0 : W0@t writes h0[t]    -> slot t&1     ; W0/WX@t read h0[t-1] -> (t+1)&1
    //  XG1: WX@t writes xg1[t-1] -> slot (t+1)&1 ; W1@t reads xg1[t-2] -> slot t&1
    //  H1 : W1@t writes h1[t-2]  -> slot t&1     ; W1/WF@t read h1[t-3] -> (t+1)&1
    //  Rb : WF-private (same-wave write->read, lgkmcnt-ordered)
    for (int t = 0; t <= TT + 3; ++t) {
        const int sp = (t + 1) & 1;
        const int sc = t & 1;

        if (wid == 0) {            // ---- XA: xg0[t+1]
            const int tn = (t + 2 < TT) ? t + 2 : TT - 1;
            f32x4 xn03 = *reinterpret_cast<const f32x4*>(xrow + (size_t)tn * II);
            f32x2 xn45 = *reinterpret_cast<const f32x2*>(xrow + (size_t)tn * II + 4);
            f16x8 a2;
            #pragma unroll
            for (int i = 0; i < 6; ++i) a2[i] = (_Float16)xc[i];
            a2[6] = (_Float16)0.f; a2[7] = (_Float16)0.f;
            #pragma unroll
            for (int m = 0; m < 16; ++m) {
                f32x4 acc = MFMA(a2, fragG[m], zero4);
                if (t + 1 < TT && lane < 16) XG0[sp][16 * m + n] = acc[0] + bv[m];
            }
            xc[0] = xn03[0]; xc[1] = xn03[1]; xc[2] = xn03[2];
            xc[3] = xn03[3]; xc[4] = xn45[0]; xc[5] = xn45[1];
        } else if (wid == 1) {     // ---- W0: layer0 @ t (in-wave recurrence)
            const f16x8 a0 = *reinterpret_cast<const f16x8*>(&H0[sp][8 * q]);
            const f16x8 a1 = *reinterpret_cast<const f16x8*>(&H0[sp][32 + 8 * q]);
            float gv[16];
            #pragma unroll
            for (int m = 0; m < 16; ++m) {
                float xgv = XG0[sc][16 * m + n];
                f32x4 acc0 = MFMA(a0, fragG[2 * m + 0], zero4);
                f32x4 acc1 = MFMA(a1, fragG[2 * m + 1], zero4);
                gv[m] = (acc0[0] + acc1[0]) + xgv;
            }
            if (t < TT) {
                #pragma unroll
                for (int j = 0; j < 4; ++j) {   // unit u = 16j+n
                    float i_ = fast_sig(gv[j]),      f_ = fast_sig(gv[4 + j]);
                    float g_ = fast_tanh(gv[8 + j]), o_ = fast_sig(gv[12 + j]);
                    cst[j] = f_ * cst[j] + i_ * g_;
                    float h = o_ * fast_tanh(cst[j]);
                    if (lane < 16) H0[sc][16 * j + n] = (_Float16)h;
                }
            }
        } else if (wid == 2) {     // ---- WX: xg1[t-1]
            const f16x8 a0 = *reinterpret_cast<const f16x8*>(&H0[sp][8 * q]);
            const f16x8 a1 = *reinterpret_cast<const f16x8*>(&H0[sp][32 + 8 * q]);
            #pragma unroll
            for (int m = 0; m < 16; ++m) {
                f32x4 acc0 = MFMA(a0, fragG[2 * m + 0], zero4);
                f32x4 acc1 = MFMA(a1, fragG[2 * m + 1], zero4);
                if (t >= 1 && t <= TT && lane < 16)
                    XG1[sp][16 * m + n] = (acc0[0] + acc1[0]) + bv[m];
            }
        } else if (wid == 3) {     // ---- W1: layer1 @ s2 = t-2 (in-wave recurrence)
            const int s2 = t - 2;
            const f16x8 a0 = *reinterpret_cast<const f16x8*>(&H1[sp][8 * q]);
            const f16x8 a1 = *reinterpret_cast<const f16x8*>(&H1[sp][32 + 8 * q]);
            float gv[16];
            #pragma unroll
            for (int m = 0; m < 16; ++m) {
                float xgv = XG1[sc][16 * m + n];
                f32x4 acc0 = MFMA(a0, fragG[2 * m + 0], zero4);
                f32x4 acc1 = MFMA(a1, fragG[2 * m + 1], zero4);
                gv[m] = (acc0[0] + acc1[0]) + xgv;
            }
            if (s2 >= 0 && s2 < TT) {
                #pragma unroll
                for (int j = 0; j < 4; ++j) {
                    float i_ = fast_sig(gv[j]),      f_ = fast_sig(gv[4 + j]);
                    float g_ = fast_tanh(gv[8 + j]), o_ = fast_sig(gv[12 + j]);
                    cst[j] = f_ * cst[j] + i_ * g_;
                    float h = o_ * fast_tanh(cst[j]);
                    if (lane < 16) H1[sc][16 * j + n] = (_Float16)h;
                }
            }
        } else {                   // ---- WF: FC2 @ s4 (reg frags), FC1 @ s3 -> Rb
            const int s3 = t - 3, s4 = t - 4;
            f32x4 o0 = MFMA(rf0, fragY[0], zero4);
            f32x4 o1 = MFMA(rf1, fragY[1], zero4);
            if (s4 >= 0 && s4 < TT && lane < OO)
                outrow[(size_t)s4 * OO + lane] = (o0[0] + o1[0]) + bf2v;
            const f16x8 a0 = *reinterpret_cast<const f16x8*>(&H1[sp][8 * q]);
            const f16x8 a1 = *reinterpret_cast<const f16x8*>(&H1[sp][32 + 8 * q]);
            #pragma unroll
            for (int m = 0; m < 4; ++m) {
                f32x4 f0 = MFMA(a0, fragG[2 * m + 0], zero4);
                f32x4 f1 = MFMA(a1, fragG[2 * m + 1], zero4);
                float r = fmaxf((f0[0] + f1[0]) + bv[m], 0.f);
                if (lane < 16) Rb[16 * m + n] = (_Float16)r;   // garbage ok: s4-guarded
            }
            // same-wave readback for next epoch's FC2 (lgkmcnt orders write->read)
            rf0 = *reinterpret_cast<const f16x8*>(&Rb[8 * q]);
            rf1 = *reinterpret_cast<const f16x8*>(&Rb[32 + 8 * q]);
        }
        LGKM_BARRIER();   // one barrier per step; global ops stay in flight
    }
}

extern "C" void kernel_launch(void* const* d_in, const int* in_sizes, int n_in,
                              void* d_out, int out_size, void* d_ws, size_t ws_size,
                              hipStream_t stream) {
    const float* xp   = (const float*)d_in[0];
    const float* Wih0 = (const float*)d_in[1];
    const float* Whh0 = (const float*)d_in[2];
    const float* b0   = (const float*)d_in[3];
    const float* Wih1 = (const float*)d_in[4];
    const float* Whh1 = (const float*)d_in[5];
    const float* b1   = (const float*)d_in[6];
    const float* W1   = (const float*)d_in[7];
    const float* bf1  = (const float*)d_in[8];
    const float* W2   = (const float*)d_in[9];
    const float* bf2  = (const float*)d_in[10];
    float* outp = (float*)d_out;

    lstm_mfma_kernel<<<dim3(256), dim3(NTHR), 0, stream>>>(
        xp, Wih0, Whh0, b0, Wih1, Whh1, b1, W1, bf1, W2, bf2, outp);
}